// Round 5
// baseline (3131.688 us; speedup 1.0000x reference)
//
#include <hip/hip_runtime.h>

// ---------------- problem constants ----------------
#define T_LEN 2048
#define B_SZ  4
#define D_DIM 2048
#define H_DIM 8192
#define BT    (B_SZ * T_LEN)

typedef float f32x4 __attribute__((ext_vector_type(4)));
typedef int   i32x4v __attribute__((ext_vector_type(4)));

// ---------------- block reduction (blockDim == 256) ----------------
__device__ __forceinline__ float block_sum(float v, float* red) {
    #pragma unroll
    for (int o = 32; o > 0; o >>= 1) v += __shfl_down(v, o, 64);
    const int lane = threadIdx.x & 63, w = threadIdx.x >> 6;
    if (lane == 0) red[w] = v;
    __syncthreads();
    float r = red[0] + red[1] + red[2] + red[3];
    __syncthreads();
    return r;
}

// ---------------- weight scale: partial abs-sum ----------------
__global__ void wabs_partial(const float* __restrict__ w, int n,
                             float* __restrict__ part) {
    __shared__ float red[16];
    float s = 0.f;
    int i = (blockIdx.x * 256 + threadIdx.x) * 8;
    const int stride = gridDim.x * 256 * 8;
    for (; i < n; i += stride) {
        f32x4 a = *(const f32x4*)(w + i);
        f32x4 b = *(const f32x4*)(w + i + 4);
        #pragma unroll
        for (int j = 0; j < 4; j++) s += fabsf(a[j]) + fabsf(b[j]);
    }
    float tot = block_sum(s, red);
    if (threadIdx.x == 0) part[blockIdx.x] = tot;
}

__global__ void wfinal(const float* __restrict__ part, int nparts, int n,
                       float* __restrict__ outp) {
    __shared__ float red[16];
    float s = 0.f;
    for (int i = threadIdx.x; i < nparts; i += 256) s += part[i];
    float tot = block_sum(s, red);
    if (threadIdx.x == 0) outp[0] = fmaxf(tot / (float)n, 1e-8f);
}

// ---------------- ternary weight quant ----------------
__global__ void wquant(const float* __restrict__ w, const float* __restrict__ sp,
                       signed char* __restrict__ q, int n) {
    const float s = *sp;
    int i = (blockIdx.x * 256 + threadIdx.x) * 16;
    const int stride = gridDim.x * 256 * 16;
    for (; i < n; i += stride) {
        union { signed char c[16]; i32x4v v; } pk;
        #pragma unroll
        for (int h = 0; h < 4; h++) {
            f32x4 a = *(const f32x4*)(w + i + h * 4);
            #pragma unroll
            for (int j = 0; j < 4; j++)
                pk.c[h * 4 + j] =
                    (signed char)(int)rintf(fminf(fmaxf(a[j] / s, -1.f), 1.f));
        }
        *(i32x4v*)(q + i) = pk.v;
    }
}

// ---------------- LN + act quant (8 elems/thread, D=2048) ----------------
__device__ __forceinline__ void ln_quant8(const float* xm_in,
                                          const float* __restrict__ g,
                                          const float* __restrict__ b,
                                          signed char* qrow, float* srow, float* red) {
    const int base = threadIdx.x * 8;
    float xm[8];
    float s = 0.f;
    #pragma unroll
    for (int j = 0; j < 8; j++) { xm[j] = xm_in[j]; s += xm[j]; }
    const float mean = block_sum(s, red) * (1.f / D_DIM);
    float s2 = 0.f;
    #pragma unroll
    for (int j = 0; j < 8; j++) { float d = xm[j] - mean; s2 += d * d; }
    const float var  = block_sum(s2, red) * (1.f / D_DIM);
    const float rstd = 1.f / sqrtf(var + 1e-5f);
    f32x4 ga = *(const f32x4*)(g + base), gb = *(const f32x4*)(g + base + 4);
    f32x4 ba = *(const f32x4*)(b + base), bb2 = *(const f32x4*)(b + base + 4);
    float gg[8] = {ga[0],ga[1],ga[2],ga[3],gb[0],gb[1],gb[2],gb[3]};
    float bb[8] = {ba[0],ba[1],ba[2],ba[3],bb2[0],bb2[1],bb2[2],bb2[3]};
    float sa = 0.f;
    #pragma unroll
    for (int j = 0; j < 8; j++) {
        xm[j] = (xm[j] - mean) * rstd * gg[j] + bb[j];
        sa += fabsf(xm[j]);
    }
    const float amean = block_sum(sa, red) * (1.f / D_DIM);
    const float scale = fmaxf(amean, 1e-8f) * 2.5f / 127.0f;
    union { signed char c[8]; int2 v; } pk;
    #pragma unroll
    for (int j = 0; j < 8; j++)
        pk.c[j] = (signed char)(int)rintf(fminf(fmaxf(xm[j] / scale, -127.f), 127.f));
    *(int2*)(qrow + base) = pk.v;
    if (threadIdx.x == 0) *srow = scale;
}

// ------- token shift + both LN/quant paths + out2 passthrough (f32) -------
__global__ void act_prep(const float* __restrict__ x, int row0,
                         const float* __restrict__ muk,
                         const float* __restrict__ gk, const float* __restrict__ bk,
                         const float* __restrict__ mur,
                         const float* __restrict__ gr, const float* __restrict__ br,
                         signed char* __restrict__ qk, float* __restrict__ sk,
                         signed char* __restrict__ qr, float* __restrict__ sr,
                         float* __restrict__ out2) {
    __shared__ float red[16];
    const int lrow = blockIdx.x;
    const int row = row0 + lrow;
    const int t = row & (T_LEN - 1);
    const int base = threadIdx.x * 8;

    float xv[8], xp[8];
    f32x4 xa = *(const f32x4*)(x + (size_t)row * D_DIM + base);
    f32x4 xb = *(const f32x4*)(x + (size_t)row * D_DIM + base + 4);
    xv[0]=xa[0]; xv[1]=xa[1]; xv[2]=xa[2]; xv[3]=xa[3];
    xv[4]=xb[0]; xv[5]=xb[1]; xv[6]=xb[2]; xv[7]=xb[3];
    if (t > 0) {
        f32x4 pa = *(const f32x4*)(x + (size_t)(row - 1) * D_DIM + base);
        f32x4 pb = *(const f32x4*)(x + (size_t)(row - 1) * D_DIM + base + 4);
        xp[0]=pa[0]; xp[1]=pa[1]; xp[2]=pa[2]; xp[3]=pa[3];
        xp[4]=pb[0]; xp[5]=pb[1]; xp[6]=pb[2]; xp[7]=pb[3];
    } else {
        #pragma unroll
        for (int j = 0; j < 8; j++) xp[j] = 0.f;
    }
    if (t == T_LEN - 1) {
        const int bb = row / T_LEN;
        *(f32x4*)(out2 + (size_t)bb * D_DIM + base)     = xa;   // f32 x[:, -1, :]
        *(f32x4*)(out2 + (size_t)bb * D_DIM + base + 4) = xb;
    }
    float mk[8], mr[8], xmk[8], xmr[8];
    f32x4 mka = *(const f32x4*)(muk + base), mkb = *(const f32x4*)(muk + base + 4);
    f32x4 mra = *(const f32x4*)(mur + base), mrb = *(const f32x4*)(mur + base + 4);
    mk[0]=mka[0]; mk[1]=mka[1]; mk[2]=mka[2]; mk[3]=mka[3];
    mk[4]=mkb[0]; mk[5]=mkb[1]; mk[6]=mkb[2]; mk[7]=mkb[3];
    mr[0]=mra[0]; mr[1]=mra[1]; mr[2]=mra[2]; mr[3]=mra[3];
    mr[4]=mrb[0]; mr[5]=mrb[1]; mr[6]=mrb[2]; mr[7]=mrb[3];
    #pragma unroll
    for (int j = 0; j < 8; j++) {
        const float dx = xp[j] - xv[j];
        xmk[j] = xv[j] + dx * mk[j];
        xmr[j] = xv[j] + dx * mr[j];
    }
    ln_quant8(xmk, gk, bk, qk + (size_t)lrow * D_DIM, sk + lrow, red);
    ln_quant8(xmr, gr, br, qr + (size_t)lrow * D_DIM, sr + lrow, red);
}

// -------- LN + act quant over H=8192 (k_act f32 rows) --------
__global__ void lnq_v(const float* __restrict__ kact,
                      const float* __restrict__ g, const float* __restrict__ b,
                      signed char* __restrict__ qv, float* __restrict__ sv) {
    __shared__ float red[16];
    const int row = blockIdx.x;
    const int base = threadIdx.x * 32;
    const float* kr = kact + (size_t)row * H_DIM + base;

    float v[32];
    float s = 0.f;
    #pragma unroll
    for (int c = 0; c < 8; c++) {
        f32x4 a = *(const f32x4*)(kr + c * 4);
        #pragma unroll
        for (int j = 0; j < 4; j++) { v[c * 4 + j] = a[j]; s += a[j]; }
    }
    const float mean = block_sum(s, red) * (1.f / H_DIM);
    float s2 = 0.f;
    #pragma unroll
    for (int j = 0; j < 32; j++) { float d = v[j] - mean; s2 += d * d; }
    const float var  = block_sum(s2, red) * (1.f / H_DIM);
    const float rstd = 1.f / sqrtf(var + 1e-5f);
    float sa = 0.f;
    #pragma unroll
    for (int c = 0; c < 8; c++) {
        f32x4 ga = *(const f32x4*)(g + base + c * 4);
        f32x4 ba = *(const f32x4*)(b + base + c * 4);
        #pragma unroll
        for (int j = 0; j < 4; j++) {
            int k = c * 4 + j;
            v[k] = (v[k] - mean) * rstd * ga[j] + ba[j];
            sa += fabsf(v[k]);
        }
    }
    const float amean = block_sum(sa, red) * (1.f / H_DIM);
    const float scale = fmaxf(amean, 1e-8f) * 2.5f / 127.0f;
    union { signed char c[32]; i32x4v v4[2]; } pk;
    #pragma unroll
    for (int j = 0; j < 32; j++)
        pk.c[j] = (signed char)(int)rintf(fminf(fmaxf(v[j] / scale, -127.f), 127.f));
    *(i32x4v*)(qv + (size_t)row * H_DIM + base)      = pk.v4[0];
    *(i32x4v*)(qv + (size_t)row * H_DIM + base + 16) = pk.v4[1];
    if (threadIdx.x == 0) sv[row] = scale;
}

// ---------------- int8 dot4 ----------------
#if __has_builtin(__builtin_amdgcn_sdot4)
__device__ __forceinline__ int dot4(int a, int b, int c) {
    return __builtin_amdgcn_sdot4(a, b, c, false);
}
#else
__device__ __forceinline__ int dot4(int a, int b, int c) {
    c += (int)(signed char)(a)       * (int)(signed char)(b);
    c += (int)(signed char)(a >> 8)  * (int)(signed char)(b >> 8);
    c += (int)(signed char)(a >> 16) * (int)(signed char)(b >> 16);
    c += (int)(signed char)(a >> 24) * (int)(signed char)(b >> 24);
    return c;
}
#endif

// ---------------- simple tiled i8 GEMM (layout-bulletproof) ----------------
// C[m,n] = sa[m]*sw * sum_k A[m,k]*B[n,k].  Tile 128(M)x64(N), K-step 64.
// EP: 0 = relu(v)^2 -> f32 (kact);  1 = sigmoid(v) -> f32 (gate);
//     2 = out_f32 = gate * v.
template <int EP>
__global__ __launch_bounds__(256) void gemm_s(
    const signed char* __restrict__ A, const signed char* __restrict__ B,
    int K, int Nn,
    const float* __restrict__ sa, const float* __restrict__ swp,
    const float* __restrict__ gate, float* __restrict__ out_f) {
    __shared__ __align__(16) signed char As[128][112];   // 64B data + pad
    __shared__ __align__(16) signed char Bs[64][112];
    const int tid = threadIdx.x;
    const int bm = blockIdx.x, bn = blockIdx.y;
    const int ty = tid >> 4, tx = tid & 15;
    const size_t arow0 = (size_t)bm * 128;
    const size_t brow0 = (size_t)bn * 64;

    int acc[8][4] = {};

    for (int k0 = 0; k0 < K; k0 += 64) {
        __syncthreads();
        #pragma unroll
        for (int i = 0; i < 2; i++) {
            int c = i * 256 + tid;
            int r = c >> 2, off = (c & 3) * 16;
            *(i32x4v*)&As[r][off] =
                *(const i32x4v*)(A + (arow0 + r) * (size_t)K + k0 + off);
        }
        {
            int r = tid >> 2, off = (tid & 3) * 16;
            *(i32x4v*)&Bs[r][off] =
                *(const i32x4v*)(B + (brow0 + r) * (size_t)K + k0 + off);
        }
        __syncthreads();

        #pragma unroll
        for (int kq = 0; kq < 4; kq++) {
            i32x4v bv[4], av[8];
            #pragma unroll
            for (int c = 0; c < 4; c++) bv[c] = *(const i32x4v*)&Bs[tx * 4 + c][kq * 16];
            #pragma unroll
            for (int r = 0; r < 8; r++) av[r] = *(const i32x4v*)&As[ty * 8 + r][kq * 16];
            #pragma unroll
            for (int r = 0; r < 8; r++)
                #pragma unroll
                for (int c = 0; c < 4; c++)
                    #pragma unroll
                    for (int w = 0; w < 4; w++)
                        acc[r][c] = dot4(av[r][w], bv[c][w], acc[r][c]);
        }
    }

    const float sw = *swp;
    #pragma unroll
    for (int r = 0; r < 8; r++) {
        const int lrow = bm * 128 + ty * 8 + r;
        const float sm = sa[lrow] * sw;
        #pragma unroll
        for (int c = 0; c < 4; c++) {
            const int gcol = bn * 64 + tx * 4 + c;
            const float v = (float)acc[r][c] * sm;
            const size_t idx = (size_t)lrow * Nn + gcol;
            if (EP == 0) {
                float rv = fmaxf(v, 0.f);
                out_f[idx] = rv * rv;
            } else if (EP == 1) {
                out_f[idx] = 1.0f / (1.0f + expf(-v));
            } else {
                out_f[idx] = gate[idx] * v;
            }
        }
    }
}

extern "C" void kernel_launch(void* const* d_in, const int* in_sizes, int n_in,
                              void* d_out, int out_size, void* d_ws, size_t ws_size,
                              hipStream_t stream) {
    const float* x   = (const float*)d_in[0];
    const float* muk = (const float*)d_in[1];
    const float* mur = (const float*)d_in[2];
    const float* wk  = (const float*)d_in[3];
    const float* gk  = (const float*)d_in[4];
    const float* bk  = (const float*)d_in[5];
    const float* wr  = (const float*)d_in[6];
    const float* gr  = (const float*)d_in[7];
    const float* br  = (const float*)d_in[8];
    const float* wv  = (const float*)d_in[9];
    const float* gv  = (const float*)d_in[10];
    const float* bv  = (const float*)d_in[11];

    // ---- adaptive workspace layout (pure function of ws_size) ----
    char* wsb = (char*)d_ws;
    size_t off = 0;
    auto alloc = [&](size_t bytes) -> size_t {
        size_t p = off;
        off = (off + bytes + 255) & ~(size_t)255;
        return p;
    };
    const size_t o_wqk  = alloc((size_t)H_DIM * D_DIM);
    const size_t o_wqr  = alloc((size_t)D_DIM * D_DIM);
    const size_t o_wqv  = alloc((size_t)D_DIM * H_DIM);
    const size_t o_wsc  = alloc(64);
    const size_t o_part = alloc(3 * 1024 * sizeof(float));
    const size_t fixed  = off;

    // per-chunk: xqk(CH*D)+xqr(CH*D)+xqv(CH*H)+kact(CH*H*4)+gate(CH*D*4)+scales(3*CH*4)
    int CH = BT;
    while (CH > 128 &&
           fixed + (size_t)CH * (D_DIM + D_DIM + H_DIM + 4 * H_DIM + 4 * D_DIM + 12) + 8192 > ws_size)
        CH >>= 1;
    const size_t o_xqk  = alloc((size_t)CH * D_DIM);
    const size_t o_xqr  = alloc((size_t)CH * D_DIM);
    const size_t o_xqv  = alloc((size_t)CH * H_DIM);
    const size_t o_kact = alloc((size_t)CH * H_DIM * 4);
    const size_t o_gate = alloc((size_t)CH * D_DIM * 4);
    const size_t o_sk   = alloc((size_t)CH * 4);
    const size_t o_sr   = alloc((size_t)CH * 4);
    const size_t o_sv   = alloc((size_t)CH * 4);

    signed char* wqk = (signed char*)(wsb + o_wqk);
    signed char* wqr = (signed char*)(wsb + o_wqr);
    signed char* wqv = (signed char*)(wsb + o_wqv);
    float* wsc  = (float*)(wsb + o_wsc);
    float* part = (float*)(wsb + o_part);
    signed char* xqk = (signed char*)(wsb + o_xqk);
    signed char* xqr = (signed char*)(wsb + o_xqr);
    signed char* xqv = (signed char*)(wsb + o_xqv);
    float* kact = (float*)(wsb + o_kact);
    float* gate = (float*)(wsb + o_gate);
    float* sk = (float*)(wsb + o_sk);
    float* sr = (float*)(wsb + o_sr);
    float* sv = (float*)(wsb + o_sv);

    float* outp = (float*)d_out;                 // f32 output!
    float* out2 = outp + (size_t)BT * D_DIM;     // f32 last-token passthrough

    // ---- weight scales + ternary quant ----
    wabs_partial<<<1024, 256, 0, stream>>>(wk, H_DIM * D_DIM, part + 0 * 1024);
    wabs_partial<<<1024, 256, 0, stream>>>(wr, D_DIM * D_DIM, part + 1 * 1024);
    wabs_partial<<<1024, 256, 0, stream>>>(wv, D_DIM * H_DIM, part + 2 * 1024);
    wfinal<<<1, 256, 0, stream>>>(part + 0 * 1024, 1024, H_DIM * D_DIM, wsc + 0);
    wfinal<<<1, 256, 0, stream>>>(part + 1 * 1024, 1024, D_DIM * D_DIM, wsc + 1);
    wfinal<<<1, 256, 0, stream>>>(part + 2 * 1024, 1024, D_DIM * H_DIM, wsc + 2);
    wquant<<<2048, 256, 0, stream>>>(wk, wsc + 0, wqk, H_DIM * D_DIM);
    wquant<<<2048, 256, 0, stream>>>(wr, wsc + 1, wqr, D_DIM * D_DIM);
    wquant<<<2048, 256, 0, stream>>>(wv, wsc + 2, wqv, D_DIM * H_DIM);

    // ---- row-chunked pipeline ----
    for (int row0 = 0; row0 < BT; row0 += CH) {
        act_prep<<<CH, 256, 0, stream>>>(x, row0, muk, gk, bk, mur, gr, br,
                                         xqk, sk, xqr, sr, out2);

        // gate = sigmoid(bitlinear_r)  (f32)
        gemm_s<1><<<dim3(CH / 128, D_DIM / 64), 256, 0, stream>>>(
            xqr, wqr, D_DIM, D_DIM, sr, wsc + 1, (const float*)nullptr, gate);

        // kact = relu(bitlinear_k)^2  (f32)
        gemm_s<0><<<dim3(CH / 128, H_DIM / 64), 256, 0, stream>>>(
            xqk, wqk, D_DIM, H_DIM, sk, wsc + 0, (const float*)nullptr, kact);

        lnq_v<<<CH, 256, 0, stream>>>(kact, gv, bv, xqv, sv);

        // out = gate * bitlinear_v  (f32 -> d_out)
        gemm_s<2><<<dim3(CH / 128, D_DIM / 64), 256, 0, stream>>>(
            xqv, wqv, H_DIM, D_DIM, sv, wsc + 2,
            gate, outp + (size_t)row0 * D_DIM);
    }
}

// Round 6
// 751.668 us; speedup vs baseline: 4.1663x; 4.1663x over previous
//
#include <hip/hip_runtime.h>

// ---------------- problem constants ----------------
#define T_LEN 2048
#define B_SZ  4
#define D_DIM 2048
#define H_DIM 8192
#define BT    (B_SZ * T_LEN)

typedef float f32x4 __attribute__((ext_vector_type(4)));
typedef int   i32x4v __attribute__((ext_vector_type(4)));
typedef int   i32x16v __attribute__((ext_vector_type(16)));

// ---------------- block reduction (blockDim == 256) ----------------
__device__ __forceinline__ float block_sum(float v, float* red) {
    #pragma unroll
    for (int o = 32; o > 0; o >>= 1) v += __shfl_down(v, o, 64);
    const int lane = threadIdx.x & 63, w = threadIdx.x >> 6;
    if (lane == 0) red[w] = v;
    __syncthreads();
    float r = red[0] + red[1] + red[2] + red[3];
    __syncthreads();
    return r;
}

// ---------------- weight scale: partial abs-sum ----------------
__global__ void wabs_partial(const float* __restrict__ w, int n,
                             float* __restrict__ part) {
    __shared__ float red[16];
    float s = 0.f;
    int i = (blockIdx.x * 256 + threadIdx.x) * 8;
    const int stride = gridDim.x * 256 * 8;
    for (; i < n; i += stride) {
        f32x4 a = *(const f32x4*)(w + i);
        f32x4 b = *(const f32x4*)(w + i + 4);
        #pragma unroll
        for (int j = 0; j < 4; j++) s += fabsf(a[j]) + fabsf(b[j]);
    }
    float tot = block_sum(s, red);
    if (threadIdx.x == 0) part[blockIdx.x] = tot;
}

__global__ void wfinal(const float* __restrict__ part, int nparts, int n,
                       float* __restrict__ outp) {
    __shared__ float red[16];
    float s = 0.f;
    for (int i = threadIdx.x; i < nparts; i += 256) s += part[i];
    float tot = block_sum(s, red);
    if (threadIdx.x == 0) outp[0] = fmaxf(tot / (float)n, 1e-8f);
}

// ---------------- ternary weight quant ----------------
__global__ void wquant(const float* __restrict__ w, const float* __restrict__ sp,
                       signed char* __restrict__ q, int n) {
    const float s = *sp;
    int i = (blockIdx.x * 256 + threadIdx.x) * 16;
    const int stride = gridDim.x * 256 * 16;
    for (; i < n; i += stride) {
        union { signed char c[16]; i32x4v v; } pk;
        #pragma unroll
        for (int h = 0; h < 4; h++) {
            f32x4 a = *(const f32x4*)(w + i + h * 4);
            #pragma unroll
            for (int j = 0; j < 4; j++)
                pk.c[h * 4 + j] =
                    (signed char)(int)rintf(fminf(fmaxf(a[j] / s, -1.f), 1.f));
        }
        *(i32x4v*)(q + i) = pk.v;
    }
}

// ---------------- LN + act quant (8 elems/thread, D=2048) ----------------
__device__ __forceinline__ void ln_quant8(const float* xm_in,
                                          const float* __restrict__ g,
                                          const float* __restrict__ b,
                                          signed char* qrow, float* srow, float* red) {
    const int base = threadIdx.x * 8;
    float xm[8];
    float s = 0.f;
    #pragma unroll
    for (int j = 0; j < 8; j++) { xm[j] = xm_in[j]; s += xm[j]; }
    const float mean = block_sum(s, red) * (1.f / D_DIM);
    float s2 = 0.f;
    #pragma unroll
    for (int j = 0; j < 8; j++) { float d = xm[j] - mean; s2 += d * d; }
    const float var  = block_sum(s2, red) * (1.f / D_DIM);
    const float rstd = 1.f / sqrtf(var + 1e-5f);
    f32x4 ga = *(const f32x4*)(g + base), gb = *(const f32x4*)(g + base + 4);
    f32x4 ba = *(const f32x4*)(b + base), bb2 = *(const f32x4*)(b + base + 4);
    float gg[8] = {ga[0],ga[1],ga[2],ga[3],gb[0],gb[1],gb[2],gb[3]};
    float bb[8] = {ba[0],ba[1],ba[2],ba[3],bb2[0],bb2[1],bb2[2],bb2[3]};
    float sa = 0.f;
    #pragma unroll
    for (int j = 0; j < 8; j++) {
        xm[j] = (xm[j] - mean) * rstd * gg[j] + bb[j];
        sa += fabsf(xm[j]);
    }
    const float amean = block_sum(sa, red) * (1.f / D_DIM);
    const float scale = fmaxf(amean, 1e-8f) * 2.5f / 127.0f;
    union { signed char c[8]; int2 v; } pk;
    #pragma unroll
    for (int j = 0; j < 8; j++)
        pk.c[j] = (signed char)(int)rintf(fminf(fmaxf(xm[j] / scale, -127.f), 127.f));
    *(int2*)(qrow + base) = pk.v;
    if (threadIdx.x == 0) *srow = scale;
}

// ------- token shift + both LN/quant paths + out2 passthrough (f32) -------
__global__ void act_prep(const float* __restrict__ x, int row0,
                         const float* __restrict__ muk,
                         const float* __restrict__ gk, const float* __restrict__ bk,
                         const float* __restrict__ mur,
                         const float* __restrict__ gr, const float* __restrict__ br,
                         signed char* __restrict__ qk, float* __restrict__ sk,
                         signed char* __restrict__ qr, float* __restrict__ sr,
                         float* __restrict__ out2) {
    __shared__ float red[16];
    const int lrow = blockIdx.x;
    const int row = row0 + lrow;
    const int t = row & (T_LEN - 1);
    const int base = threadIdx.x * 8;

    float xv[8], xp[8];
    f32x4 xa = *(const f32x4*)(x + (size_t)row * D_DIM + base);
    f32x4 xb = *(const f32x4*)(x + (size_t)row * D_DIM + base + 4);
    xv[0]=xa[0]; xv[1]=xa[1]; xv[2]=xa[2]; xv[3]=xa[3];
    xv[4]=xb[0]; xv[5]=xb[1]; xv[6]=xb[2]; xv[7]=xb[3];
    if (t > 0) {
        f32x4 pa = *(const f32x4*)(x + (size_t)(row - 1) * D_DIM + base);
        f32x4 pb = *(const f32x4*)(x + (size_t)(row - 1) * D_DIM + base + 4);
        xp[0]=pa[0]; xp[1]=pa[1]; xp[2]=pa[2]; xp[3]=pa[3];
        xp[4]=pb[0]; xp[5]=pb[1]; xp[6]=pb[2]; xp[7]=pb[3];
    } else {
        #pragma unroll
        for (int j = 0; j < 8; j++) xp[j] = 0.f;
    }
    if (t == T_LEN - 1) {
        const int bb = row / T_LEN;
        *(f32x4*)(out2 + (size_t)bb * D_DIM + base)     = xa;   // f32 x[:, -1, :]
        *(f32x4*)(out2 + (size_t)bb * D_DIM + base + 4) = xb;
    }
    float mk[8], mr[8], xmk[8], xmr[8];
    f32x4 mka = *(const f32x4*)(muk + base), mkb = *(const f32x4*)(muk + base + 4);
    f32x4 mra = *(const f32x4*)(mur + base), mrb = *(const f32x4*)(mur + base + 4);
    mk[0]=mka[0]; mk[1]=mka[1]; mk[2]=mka[2]; mk[3]=mka[3];
    mk[4]=mkb[0]; mk[5]=mkb[1]; mk[6]=mkb[2]; mk[7]=mkb[3];
    mr[0]=mra[0]; mr[1]=mra[1]; mr[2]=mra[2]; mr[3]=mra[3];
    mr[4]=mrb[0]; mr[5]=mrb[1]; mr[6]=mrb[2]; mr[7]=mrb[3];
    #pragma unroll
    for (int j = 0; j < 8; j++) {
        const float dx = xp[j] - xv[j];
        xmk[j] = xv[j] + dx * mk[j];
        xmr[j] = xv[j] + dx * mr[j];
    }
    ln_quant8(xmk, gk, bk, qk + (size_t)lrow * D_DIM, sk + lrow, red);
    ln_quant8(xmr, gr, br, qr + (size_t)lrow * D_DIM, sr + lrow, red);
}

// -------- LN + act quant over H=8192 (k_act f32 rows) --------
__global__ void lnq_v(const float* __restrict__ kact,
                      const float* __restrict__ g, const float* __restrict__ b,
                      signed char* __restrict__ qv, float* __restrict__ sv) {
    __shared__ float red[16];
    const int row = blockIdx.x;
    const int base = threadIdx.x * 32;
    const float* kr = kact + (size_t)row * H_DIM + base;

    float v[32];
    float s = 0.f;
    #pragma unroll
    for (int c = 0; c < 8; c++) {
        f32x4 a = *(const f32x4*)(kr + c * 4);
        #pragma unroll
        for (int j = 0; j < 4; j++) { v[c * 4 + j] = a[j]; s += a[j]; }
    }
    const float mean = block_sum(s, red) * (1.f / H_DIM);
    float s2 = 0.f;
    #pragma unroll
    for (int j = 0; j < 32; j++) { float d = v[j] - mean; s2 += d * d; }
    const float var  = block_sum(s2, red) * (1.f / H_DIM);
    const float rstd = 1.f / sqrtf(var + 1e-5f);
    float sa = 0.f;
    #pragma unroll
    for (int c = 0; c < 8; c++) {
        f32x4 ga = *(const f32x4*)(g + base + c * 4);
        f32x4 ba = *(const f32x4*)(b + base + c * 4);
        #pragma unroll
        for (int j = 0; j < 4; j++) {
            int k = c * 4 + j;
            v[k] = (v[k] - mean) * rstd * ga[j] + ba[j];
            sa += fabsf(v[k]);
        }
    }
    const float amean = block_sum(sa, red) * (1.f / H_DIM);
    const float scale = fmaxf(amean, 1e-8f) * 2.5f / 127.0f;
    union { signed char c[32]; i32x4v v4[2]; } pk;
    #pragma unroll
    for (int j = 0; j < 32; j++)
        pk.c[j] = (signed char)(int)rintf(fminf(fmaxf(v[j] / scale, -127.f), 127.f));
    *(i32x4v*)(qv + (size_t)row * H_DIM + base)      = pk.v4[0];
    *(i32x4v*)(qv + (size_t)row * H_DIM + base + 16) = pk.v4[1];
    if (threadIdx.x == 0) sv[row] = scale;
}

// ---------------- i8 MFMA GEMM: C[m,n] = sa[m]*sw * sum_k A[m,k]*B[n,k] ----------------
// 128x128 tile, BK=128 bytes, 4 waves (2x2), each wave 64x64 via 2x2 of 32x32x32 i8 MFMA.
// LDS XOR-swizzle on 16B slots: linear dest for global_load_lds, inverse-swizzled
// global source, swizzled ds_read_b128.  (Numerically verified: round3 == round4 dot4.)
// EP: 0 = relu(v)^2 -> f32 (kact);  1 = sigmoid(v) -> f32 (gate);  2 = out = gate * v (f32).
template <int EP>
__global__ __launch_bounds__(256) void gemm_i8(
    const signed char* __restrict__ A, const signed char* __restrict__ B,
    int K, int Nn,
    const float* __restrict__ sa, const float* __restrict__ swp,
    const float* __restrict__ gate, float* __restrict__ out_f) {
    __shared__ signed char As[128 * 128];
    __shared__ signed char Bs[128 * 128];
    const int tid  = threadIdx.x;
    const int bm   = blockIdx.x, bn = blockIdx.y;
    const int lane = tid & 63, wave = tid >> 6;
    const int wr = wave >> 1, wc = wave & 1;
    const int lrow = lane & 31, lhalf = lane >> 5;

    i32x16v acc[2][2] = {};

    // staging geometry: 4 x 16B per thread per matrix (linear LDS dest)
    int srow[4], scol[4];
    #pragma unroll
    for (int i = 0; i < 4; i++) {
        int o = i * 256 + tid;
        int r = o >> 3, sl = o & 7;
        srow[i] = r;
        scol[i] = ((sl ^ (r & 7)) * 16);   // inverse-swizzled global source
    }
    const size_t arow0 = (size_t)bm * 128;
    const size_t brow0 = (size_t)bn * 128;

    for (int k0 = 0; k0 < K; k0 += 128) {
        __syncthreads();   // previous compute done before overwrite
        #pragma unroll
        for (int i = 0; i < 4; i++) {
            const signed char* ga = A + (arow0 + srow[i]) * (size_t)K + k0 + scol[i];
            const signed char* gb = B + (brow0 + srow[i]) * (size_t)K + k0 + scol[i];
            __builtin_amdgcn_global_load_lds(
                (const __attribute__((address_space(1))) void*)ga,
                (__attribute__((address_space(3))) void*)(As + (i * 256 + tid) * 16),
                16, 0, 0);
            __builtin_amdgcn_global_load_lds(
                (const __attribute__((address_space(1))) void*)gb,
                (__attribute__((address_space(3))) void*)(Bs + (i * 256 + tid) * 16),
                16, 0, 0);
        }
        __syncthreads();   // compiler drains vmcnt before barrier

        #pragma unroll
        for (int ks = 0; ks < 4; ks++) {
            const int slot = ks * 2 + lhalf;   // 16B slot (global k units)
            i32x4v af[2], bfv[2];
            #pragma unroll
            for (int tm = 0; tm < 2; tm++) {
                int r = wr * 64 + tm * 32 + lrow;
                af[tm] = *(const i32x4v*)(As + r * 128 + ((slot ^ (r & 7)) * 16));
            }
            #pragma unroll
            for (int tn = 0; tn < 2; tn++) {
                int r = wc * 64 + tn * 32 + lrow;
                bfv[tn] = *(const i32x4v*)(Bs + r * 128 + ((slot ^ (r & 7)) * 16));
            }
            #pragma unroll
            for (int tm = 0; tm < 2; tm++)
                #pragma unroll
                for (int tn = 0; tn < 2; tn++)
                    acc[tm][tn] = __builtin_amdgcn_mfma_i32_32x32x32_i8(
                        af[tm], bfv[tn], acc[tm][tn], 0, 0, 0);
        }
    }

    const float sw = *swp;
    #pragma unroll
    for (int tm = 0; tm < 2; tm++) {
        #pragma unroll
        for (int tn = 0; tn < 2; tn++) {
            #pragma unroll
            for (int rg = 0; rg < 16; rg++) {
                const int rin  = (rg & 3) + 8 * (rg >> 2) + 4 * lhalf;
                const int grow = bm * 128 + wr * 64 + tm * 32 + rin;
                const int gcol = bn * 128 + wc * 64 + tn * 32 + lrow;
                const float v = (float)acc[tm][tn][rg] * sa[grow] * sw;
                const size_t idx = (size_t)grow * Nn + gcol;
                if (EP == 0) {
                    float rv = fmaxf(v, 0.f);
                    out_f[idx] = rv * rv;
                } else if (EP == 1) {
                    out_f[idx] = 1.0f / (1.0f + expf(-v));
                } else {
                    out_f[idx] = gate[idx] * v;
                }
            }
        }
    }
}

extern "C" void kernel_launch(void* const* d_in, const int* in_sizes, int n_in,
                              void* d_out, int out_size, void* d_ws, size_t ws_size,
                              hipStream_t stream) {
    const float* x   = (const float*)d_in[0];
    const float* muk = (const float*)d_in[1];
    const float* mur = (const float*)d_in[2];
    const float* wk  = (const float*)d_in[3];
    const float* gk  = (const float*)d_in[4];
    const float* bk  = (const float*)d_in[5];
    const float* wr  = (const float*)d_in[6];
    const float* gr  = (const float*)d_in[7];
    const float* br  = (const float*)d_in[8];
    const float* wv  = (const float*)d_in[9];
    const float* gv  = (const float*)d_in[10];
    const float* bv  = (const float*)d_in[11];

    // ---- adaptive workspace layout (pure function of ws_size) ----
    char* wsb = (char*)d_ws;
    size_t off = 0;
    auto alloc = [&](size_t bytes) -> size_t {
        size_t p = off;
        off = (off + bytes + 255) & ~(size_t)255;
        return p;
    };
    const size_t o_wqk  = alloc((size_t)H_DIM * D_DIM);
    const size_t o_wqr  = alloc((size_t)D_DIM * D_DIM);
    const size_t o_wqv  = alloc((size_t)D_DIM * H_DIM);
    const size_t o_wsc  = alloc(64);
    const size_t o_part = alloc(3 * 1024 * sizeof(float));
    const size_t fixed  = off;

    // per-chunk: xqk(CH*D)+xqr(CH*D)+xqv(CH*H)+kact(CH*H*4)+gate(CH*D*4)+scales(3*CH*4)
    int CH = BT;
    while (CH > 128 &&
           fixed + (size_t)CH * (D_DIM + D_DIM + H_DIM + 4 * H_DIM + 4 * D_DIM + 12) + 8192 > ws_size)
        CH >>= 1;
    const size_t o_xqk  = alloc((size_t)CH * D_DIM);
    const size_t o_xqr  = alloc((size_t)CH * D_DIM);
    const size_t o_xqv  = alloc((size_t)CH * H_DIM);
    const size_t o_kact = alloc((size_t)CH * H_DIM * 4);
    const size_t o_gate = alloc((size_t)CH * D_DIM * 4);
    const size_t o_sk   = alloc((size_t)CH * 4);
    const size_t o_sr   = alloc((size_t)CH * 4);
    const size_t o_sv   = alloc((size_t)CH * 4);

    signed char* wqk = (signed char*)(wsb + o_wqk);
    signed char* wqr = (signed char*)(wsb + o_wqr);
    signed char* wqv = (signed char*)(wsb + o_wqv);
    float* wsc  = (float*)(wsb + o_wsc);
    float* part = (float*)(wsb + o_part);
    signed char* xqk = (signed char*)(wsb + o_xqk);
    signed char* xqr = (signed char*)(wsb + o_xqr);
    signed char* xqv = (signed char*)(wsb + o_xqv);
    float* kact = (float*)(wsb + o_kact);
    float* gate = (float*)(wsb + o_gate);
    float* sk = (float*)(wsb + o_sk);
    float* sr = (float*)(wsb + o_sr);
    float* sv = (float*)(wsb + o_sv);

    float* outp = (float*)d_out;                 // f32 output
    float* out2 = outp + (size_t)BT * D_DIM;     // f32 last-token passthrough

    // ---- weight scales + ternary quant ----
    wabs_partial<<<1024, 256, 0, stream>>>(wk, H_DIM * D_DIM, part + 0 * 1024);
    wabs_partial<<<1024, 256, 0, stream>>>(wr, D_DIM * D_DIM, part + 1 * 1024);
    wabs_partial<<<1024, 256, 0, stream>>>(wv, D_DIM * H_DIM, part + 2 * 1024);
    wfinal<<<1, 256, 0, stream>>>(part + 0 * 1024, 1024, H_DIM * D_DIM, wsc + 0);
    wfinal<<<1, 256, 0, stream>>>(part + 1 * 1024, 1024, D_DIM * D_DIM, wsc + 1);
    wfinal<<<1, 256, 0, stream>>>(part + 2 * 1024, 1024, D_DIM * H_DIM, wsc + 2);
    wquant<<<2048, 256, 0, stream>>>(wk, wsc + 0, wqk, H_DIM * D_DIM);
    wquant<<<2048, 256, 0, stream>>>(wr, wsc + 1, wqr, D_DIM * D_DIM);
    wquant<<<2048, 256, 0, stream>>>(wv, wsc + 2, wqv, D_DIM * H_DIM);

    // ---- row-chunked pipeline ----
    for (int row0 = 0; row0 < BT; row0 += CH) {
        act_prep<<<CH, 256, 0, stream>>>(x, row0, muk, gk, bk, mur, gr, br,
                                         xqk, sk, xqr, sr, out2);

        // gate = sigmoid(bitlinear_r)  (f32)
        gemm_i8<1><<<dim3(CH / 128, D_DIM / 128), 256, 0, stream>>>(
            xqr, wqr, D_DIM, D_DIM, sr, wsc + 1, (const float*)nullptr, gate);

        // kact = relu(bitlinear_k)^2  (f32)
        gemm_i8<0><<<dim3(CH / 128, H_DIM / 128), 256, 0, stream>>>(
            xqk, wqk, D_DIM, H_DIM, sk, wsc + 0, (const float*)nullptr, kact);

        lnq_v<<<CH, 256, 0, stream>>>(kact, gv, bv, xqv, sv);

        // out = gate * bitlinear_v  (f32 -> d_out)
        gemm_i8<2><<<dim3(CH / 128, D_DIM / 128), 256, 0, stream>>>(
            xqv, wqv, H_DIM, D_DIM, sv, wsc + 2,
            gate, outp + (size_t)row0 * D_DIM);
    }
}